// Round 1
// baseline (562.542 us; speedup 1.0000x reference)
//
#include <hip/hip_runtime.h>
#include <hip/hip_bf16.h>
#include <stdint.h>

// MPO linear: out = x @ W^T + bias, W[m1*64+m2, n1*64+n2] = sum_r c1[m1,n1,r] c2[r,m2,n2]
// Strategy: materialize W in bf16 (4096x4096x256 GEMM, permuted epilogue store),
// then bf16 MFMA GEMM for x@W^T (m97-style 128x128 tile, global_load_lds width=16).

#define TOKENS 8192
#define DIN    4096
#define DOUT   4096
#define RANK   256

typedef __attribute__((ext_vector_type(8))) short   short8;
typedef __attribute__((ext_vector_type(4))) float   floatx4;

__device__ __forceinline__ unsigned short f2bf(float f) {
  union { float f; unsigned u; } v; v.f = f;
  unsigned r = v.u + 0x7FFFu + ((v.u >> 16) & 1u);  // round-to-nearest-even
  return (unsigned short)(r >> 16);
}

__device__ __forceinline__ void gl2lds16(const void* g, void* l) {
  __builtin_amdgcn_global_load_lds(
      (const __attribute__((address_space(1))) unsigned int*)g,
      (__attribute__((address_space(3))) unsigned int*)l,
      16, 0, 0);
}

// ---- fp32 -> bf16 convert, n multiple of 2048 ----
__global__ __launch_bounds__(256) void k_f32_to_bf16(const float* __restrict__ src,
                                                     unsigned short* __restrict__ dst,
                                                     int n) {
  int i = (blockIdx.x * 256 + threadIdx.x) * 8;
  if (i >= n) return;
  float4 a = *(const float4*)(src + i);
  float4 b = *(const float4*)(src + i + 4);
  short8 o;
  o[0] = (short)f2bf(a.x); o[1] = (short)f2bf(a.y);
  o[2] = (short)f2bf(a.z); o[3] = (short)f2bf(a.w);
  o[4] = (short)f2bf(b.x); o[5] = (short)f2bf(b.y);
  o[6] = (short)f2bf(b.z); o[7] = (short)f2bf(b.w);
  *(short8*)(dst + i) = o;
}

// ---- core2 [256][4096] f32  ->  c2t [4096][256] bf16 (LDS tile transpose) ----
__global__ __launch_bounds__(256) void k_transpose_c2(const float* __restrict__ c2,
                                                      unsigned short* __restrict__ c2t) {
  __shared__ float tile[64][65];
  const int p0 = blockIdx.x * 64;
  const int r0 = blockIdx.y * 64;
  {
    const int px = threadIdx.x & 63;
    const int rb = threadIdx.x >> 6;           // 0..3
    for (int s = 0; s < 16; ++s) {
      int r = rb + s * 4;
      tile[r][px] = c2[(size_t)(r0 + r) * 4096 + p0 + px];
    }
  }
  __syncthreads();
  {
    const int rx = threadIdx.x & 63;
    const int pb = threadIdx.x >> 6;
    for (int s = 0; s < 16; ++s) {
      int p = pb + s * 4;
      c2t[(size_t)(p0 + p) * 256 + r0 + rx] = f2bf(tile[rx][p]);
    }
  }
}

// ---- bf16 MFMA GEMM, C = A @ B^T.  A:[M][K] bf16 row-major, B:[N][K] bf16 row-major.
// 128x128 tile, BK=32, 256 threads (4 waves in 2x2), each wave 64x64 via 4x4 MFMA 16x16x32.
// PERM=false: outF[m*DOUT + n] = acc + bias[n]  (fp32)
// PERM=true : outW[(m1*64+m2)*4096 + (n1*64+n2)] = bf16(acc), m1=m>>6,n1=m&63,m2=n>>6,n2=n&63
template <int K, bool PERM>
__global__ __launch_bounds__(256) void k_gemm_bt(const unsigned short* __restrict__ A,
                                                 const unsigned short* __restrict__ B,
                                                 float* __restrict__ outF,
                                                 unsigned short* __restrict__ outW,
                                                 const float* __restrict__ bias) {
  __shared__ __align__(16) unsigned short As[128 * 32];
  __shared__ __align__(16) unsigned short Bs[128 * 32];

  const int tid  = threadIdx.x;
  const int lane = tid & 63;
  const int wave = tid >> 6;
  const int m0 = blockIdx.y * 128;
  const int n0 = blockIdx.x * 128;

  const int waveM = (wave & 1) * 64;
  const int waveN = (wave >> 1) * 64;
  const int l15  = lane & 15;
  const int quad = lane >> 4;

  floatx4 acc[4][4];
#pragma unroll
  for (int i = 0; i < 4; ++i)
#pragma unroll
    for (int j = 0; j < 4; ++j) acc[i][j] = (floatx4)0.0f;

  const size_t rowBytes = (size_t)K * 2;

  for (int kt = 0; kt < K; kt += 32) {
    __syncthreads();  // prior K-step's LDS reads done
#pragma unroll
    for (int j = 0; j < 2; ++j) {
      const int flat = (j * 4 + wave) * 1024 + lane * 16;  // byte offset in 8KB tile
      const int row  = flat >> 6;                          // /64B per 32-elem row
      const int kb   = flat & 63;
      const int ldsb = (j * 4 + wave) * 1024;              // wave-uniform base
      gl2lds16((const char*)A + (size_t)(m0 + row) * rowBytes + (size_t)kt * 2 + kb,
               (char*)As + ldsb);
      gl2lds16((const char*)B + (size_t)(n0 + row) * rowBytes + (size_t)kt * 2 + kb,
               (char*)Bs + ldsb);
    }
    __syncthreads();  // drain vmcnt, LDS visible

    short8 af[4], bf[4];
#pragma unroll
    for (int mi = 0; mi < 4; ++mi)
      af[mi] = *(const short8*)(As + (waveM + mi * 16 + l15) * 32 + quad * 8);
#pragma unroll
    for (int ni = 0; ni < 4; ++ni)
      bf[ni] = *(const short8*)(Bs + (waveN + ni * 16 + l15) * 32 + quad * 8);

#pragma unroll
    for (int mi = 0; mi < 4; ++mi)
#pragma unroll
      for (int ni = 0; ni < 4; ++ni)
        acc[mi][ni] = __builtin_amdgcn_mfma_f32_16x16x32_bf16(af[mi], bf[ni], acc[mi][ni], 0, 0, 0);
  }

  // Epilogue. C/D layout (verified m89/m91): col = lane&15, row = quad*4 + reg.
  if (!PERM) {
#pragma unroll
    for (int ni = 0; ni < 4; ++ni) {
      const int col = n0 + waveN + ni * 16 + l15;
      const float bv = bias[col];
#pragma unroll
      for (int mi = 0; mi < 4; ++mi) {
        const int rowb = m0 + waveM + mi * 16 + quad * 4;
#pragma unroll
        for (int r = 0; r < 4; ++r)
          outF[(size_t)(rowb + r) * DOUT + col] = acc[mi][ni][r] + bv;
      }
    }
  } else {
#pragma unroll
    for (int ni = 0; ni < 4; ++ni) {
      const int bcol = n0 + waveN + ni * 16 + l15;
      const int m2 = bcol >> 6, n2 = bcol & 63;
#pragma unroll
      for (int mi = 0; mi < 4; ++mi) {
        const int arow0 = m0 + waveM + mi * 16 + quad * 4;
#pragma unroll
        for (int r = 0; r < 4; ++r) {
          const int arow = arow0 + r;
          const int m1 = arow >> 6, n1 = arow & 63;
          outW[(size_t)(m1 * 64 + m2) * 4096 + (n1 * 64 + n2)] = f2bf(acc[mi][ni][r]);
        }
      }
    }
  }
}

extern "C" void kernel_launch(void* const* d_in, const int* in_sizes, int n_in,
                              void* d_out, int out_size, void* d_ws, size_t ws_size,
                              hipStream_t stream) {
  const float* x    = (const float*)d_in[0];
  const float* c1   = (const float*)d_in[1];
  const float* c2   = (const float*)d_in[2];
  const float* bias = (const float*)d_in[3];
  float* out = (float*)d_out;

  // workspace layout (100 MB total)
  char* ws = (char*)d_ws;
  unsigned short* xb  = (unsigned short*)ws;                               // 67108864 B
  unsigned short* Wb  = (unsigned short*)(ws + 67108864);                  // 33554432 B
  unsigned short* c1b = (unsigned short*)(ws + 67108864 + 33554432);       //  2097152 B
  unsigned short* c2t = (unsigned short*)(ws + 67108864 + 33554432 + 2097152);  // 2097152 B

  k_f32_to_bf16<<<(TOKENS * DIN) / 2048, 256, 0, stream>>>(x, xb, TOKENS * DIN);
  k_f32_to_bf16<<<(64 * 64 * RANK) / 2048, 256, 0, stream>>>(c1, c1b, 64 * 64 * RANK);
  k_transpose_c2<<<dim3(64, 4), 256, 0, stream>>>(c2, c2t);

  // t-GEMM: [4096 x 256] @ [4096 x 256]^T -> W bf16 (permuted store)
  k_gemm_bt<RANK, true><<<dim3(32, 32), 256, 0, stream>>>(c1b, c2t, nullptr, Wb, nullptr);
  // main GEMM: [8192 x 4096] @ [4096 x 4096]^T + bias -> out fp32
  k_gemm_bt<DIN, false><<<dim3(DOUT / 128, TOKENS / 128), 256, 0, stream>>>(xb, Wb, out, nullptr, bias);
}

// Round 3
// 552.963 us; speedup vs baseline: 1.0173x; 1.0173x over previous
//
#include <hip/hip_runtime.h>
#include <hip/hip_bf16.h>
#include <stdint.h>

// MPO linear: out = x @ W^T + bias, W[m1*64+m2, n1*64+n2] = sum_r c1[m1,n1,r] c2[r,m2,n2]
// R3: BISECT. Keep R2's XOR-swizzled LDS layout (kills ds_read_b128 bank conflicts),
//     revert W-GEMM to BK=32 (R1-proven). R2's BK=128 W-GEMM showed a timing-dependent
//     race (correct on call 1, wrong on warm calls) — suspect its 16-deep global_load_lds
//     queue / 64KB-LDS structure, not the swizzle (addresses only, fully barriered).

#define TOKENS 8192
#define DIN    4096
#define DOUT   4096
#define RANK   256

typedef __attribute__((ext_vector_type(8))) short   short8;
typedef __attribute__((ext_vector_type(4))) float   floatx4;

__device__ __forceinline__ unsigned short f2bf(float f) {
  union { float f; unsigned u; } v; v.f = f;
  unsigned r = v.u + 0x7FFFu + ((v.u >> 16) & 1u);  // round-to-nearest-even
  return (unsigned short)(r >> 16);
}

__device__ __forceinline__ void gl2lds16(const void* g, void* l) {
  __builtin_amdgcn_global_load_lds(
      (const __attribute__((address_space(1))) unsigned int*)g,
      (__attribute__((address_space(3))) unsigned int*)l,
      16, 0, 0);
}

// ---- fp32 -> bf16 convert, n multiple of 2048 ----
__global__ __launch_bounds__(256) void k_f32_to_bf16(const float* __restrict__ src,
                                                     unsigned short* __restrict__ dst,
                                                     int n) {
  int i = (blockIdx.x * 256 + threadIdx.x) * 8;
  if (i >= n) return;
  float4 a = *(const float4*)(src + i);
  float4 b = *(const float4*)(src + i + 4);
  short8 o;
  o[0] = (short)f2bf(a.x); o[1] = (short)f2bf(a.y);
  o[2] = (short)f2bf(a.z); o[3] = (short)f2bf(a.w);
  o[4] = (short)f2bf(b.x); o[5] = (short)f2bf(b.y);
  o[6] = (short)f2bf(b.z); o[7] = (short)f2bf(b.w);
  *(short8*)(dst + i) = o;
}

// ---- core2 [256][4096] f32  ->  c2t [4096][256] bf16 (LDS tile transpose) ----
__global__ __launch_bounds__(256) void k_transpose_c2(const float* __restrict__ c2,
                                                      unsigned short* __restrict__ c2t) {
  __shared__ float tile[64][65];
  const int p0 = blockIdx.x * 64;
  const int r0 = blockIdx.y * 64;
  {
    const int px = threadIdx.x & 63;
    const int rb = threadIdx.x >> 6;           // 0..3
    for (int s = 0; s < 16; ++s) {
      int r = rb + s * 4;
      tile[r][px] = c2[(size_t)(r0 + r) * 4096 + p0 + px];
    }
  }
  __syncthreads();
  {
    const int rx = threadIdx.x & 63;
    const int pb = threadIdx.x >> 6;
    for (int s = 0; s < 16; ++s) {
      int p = pb + s * 4;
      c2t[(size_t)(p0 + p) * 256 + r0 + rx] = f2bf(tile[rx][p]);
    }
  }
}

// ---- bf16 MFMA GEMM, C = A @ B^T.  A:[M][K] bf16 row-major, B:[N][K] bf16 row-major.
// 128x128 block tile, BK per K-step, 256 threads (4 waves 2x2), wave = 64x64 via 16x16x32.
// LDS layout XOR-swizzled in 16B chunks: LDS chunk c of row holds global chunk c^(row&CM).
// PERM=false: outF[m*DOUT + n] = acc + bias[n]  (fp32)
// PERM=true : outW[(m1*64+m2)*4096 + (n1*64+n2)] = bf16(acc)
template <int K, int BK, bool PERM>
__global__ __launch_bounds__(256) void k_gemm_bt(const unsigned short* __restrict__ A,
                                                 const unsigned short* __restrict__ B,
                                                 float* __restrict__ outF,
                                                 unsigned short* __restrict__ outW,
                                                 const float* __restrict__ bias) {
  constexpr int ROWB   = BK * 2;        // LDS bytes per row
  constexpr int CM     = BK / 8 - 1;    // 16B-chunk index mask within a row
  constexpr int ROUNDS = BK / 16;       // staging rounds (256 thr x 16B = 4KB each)
  constexpr int KK     = BK / 32;       // mfma k-steps per K-iteration

  __shared__ __align__(16) unsigned short As[128 * BK];
  __shared__ __align__(16) unsigned short Bs[128 * BK];

  const int tid  = threadIdx.x;
  const int lane = tid & 63;
  const int wave = tid >> 6;
  const int m0 = blockIdx.y * 128;
  const int n0 = blockIdx.x * 128;

  const int waveM = (wave & 1) * 64;
  const int waveN = (wave >> 1) * 64;
  const int l15  = lane & 15;
  const int quad = lane >> 4;

  floatx4 acc[4][4];
#pragma unroll
  for (int i = 0; i < 4; ++i)
#pragma unroll
    for (int j = 0; j < 4; ++j) acc[i][j] = (floatx4)0.0f;

  const size_t rowBytes = (size_t)K * 2;  // global row stride

  for (int kt = 0; kt < K; kt += BK) {
    __syncthreads();  // prior K-step's LDS reads done
#pragma unroll
    for (int j = 0; j < ROUNDS; ++j) {
      const int flat = (j * 4 + wave) * 1024 + lane * 16;  // byte offset in tile
      const int row  = flat / ROWB;
      const int c    = (flat >> 4) & CM;
      const int cs   = c ^ (row & CM);                     // swizzled global chunk
      const int ldsb = (j * 4 + wave) * 1024;              // wave-uniform base
      gl2lds16((const char*)A + (size_t)(m0 + row) * rowBytes + (size_t)kt * 2 + cs * 16,
               (char*)As + ldsb);
      gl2lds16((const char*)B + (size_t)(n0 + row) * rowBytes + (size_t)kt * 2 + cs * 16,
               (char*)Bs + ldsb);
    }
    __syncthreads();  // drain vmcnt, LDS visible

#pragma unroll
    for (int kk = 0; kk < KK; ++kk) {
      short8 af[4], bf[4];
#pragma unroll
      for (int mi = 0; mi < 4; ++mi) {
        const int row = waveM + mi * 16 + l15;
        const int cs  = (kk * 4 + quad) ^ (row & CM);
        af[mi] = *(const short8*)(As + row * BK + cs * 8);
      }
#pragma unroll
      for (int ni = 0; ni < 4; ++ni) {
        const int row = waveN + ni * 16 + l15;
        const int cs  = (kk * 4 + quad) ^ (row & CM);
        bf[ni] = *(const short8*)(Bs + row * BK + cs * 8);
      }
#pragma unroll
      for (int mi = 0; mi < 4; ++mi)
#pragma unroll
        for (int ni = 0; ni < 4; ++ni)
          acc[mi][ni] = __builtin_amdgcn_mfma_f32_16x16x32_bf16(af[mi], bf[ni], acc[mi][ni], 0, 0, 0);
    }
  }

  // Epilogue. C/D layout (verified m89/m91): col = lane&15, row = quad*4 + reg.
  if (!PERM) {
#pragma unroll
    for (int ni = 0; ni < 4; ++ni) {
      const int col = n0 + waveN + ni * 16 + l15;
      const float bv = bias[col];
#pragma unroll
      for (int mi = 0; mi < 4; ++mi) {
        const int rowb = m0 + waveM + mi * 16 + quad * 4;
#pragma unroll
        for (int r = 0; r < 4; ++r)
          outF[(size_t)(rowb + r) * DOUT + col] = acc[mi][ni][r] + bv;
      }
    }
  } else {
#pragma unroll
    for (int ni = 0; ni < 4; ++ni) {
      const int bcol = n0 + waveN + ni * 16 + l15;
      const int m2 = bcol >> 6, n2 = bcol & 63;
#pragma unroll
      for (int mi = 0; mi < 4; ++mi) {
        const int arow0 = m0 + waveM + mi * 16 + quad * 4;
#pragma unroll
        for (int r = 0; r < 4; ++r) {
          const int arow = arow0 + r;
          const int m1 = arow >> 6, n1 = arow & 63;
          outW[(size_t)(m1 * 64 + m2) * 4096 + (n1 * 64 + n2)] = f2bf(acc[mi][ni][r]);
        }
      }
    }
  }
}

extern "C" void kernel_launch(void* const* d_in, const int* in_sizes, int n_in,
                              void* d_out, int out_size, void* d_ws, size_t ws_size,
                              hipStream_t stream) {
  const float* x    = (const float*)d_in[0];
  const float* c1   = (const float*)d_in[1];
  const float* c2   = (const float*)d_in[2];
  const float* bias = (const float*)d_in[3];
  float* out = (float*)d_out;

  // workspace layout (100 MB total)
  char* ws = (char*)d_ws;
  unsigned short* xb  = (unsigned short*)ws;                               // 67108864 B
  unsigned short* Wb  = (unsigned short*)(ws + 67108864);                  // 33554432 B
  unsigned short* c1b = (unsigned short*)(ws + 67108864 + 33554432);       //  2097152 B
  unsigned short* c2t = (unsigned short*)(ws + 67108864 + 33554432 + 2097152);  // 2097152 B

  k_f32_to_bf16<<<(TOKENS * DIN) / 2048, 256, 0, stream>>>(x, xb, TOKENS * DIN);
  k_f32_to_bf16<<<(64 * 64 * RANK) / 2048, 256, 0, stream>>>(c1, c1b, 64 * 64 * RANK);
  k_transpose_c2<<<dim3(64, 4), 256, 0, stream>>>(c2, c2t);

  // t-GEMM: [4096 x 256] @ [4096 x 256]^T -> W bf16 (permuted store), BK=32 (R1-proven)
  k_gemm_bt<RANK, 32, true><<<dim3(32, 32), 256, 0, stream>>>(c1b, c2t, nullptr, Wb, nullptr);
  // main GEMM: [8192 x 4096] @ [4096 x 4096]^T + bias -> out fp32, BK=32
  k_gemm_bt<DIN, 32, false><<<dim3(DOUT / 128, TOKENS / 128), 256, 0, stream>>>(xb, Wb, out, nullptr, bias);
}